// Round 4
// baseline (371.667 us; speedup 1.0000x reference)
//
#include <hip/hip_runtime.h>
#include <hip/hip_bf16.h>
#include <hip/hip_cooperative_groups.h>

// Conv2dWithLoRA: out = conv3x3(x, W_eff) + b, where W_eff = W + 2.0 * B@A.
// LoRA folded into weights -> single implicit-GEMM conv, bf16 MFMA, fp32 accum.
// M = 16*64*64 = 65536 pixels, N = 256 outs, K = 128*9 = 1152.
// R1: BK=64 + XOR-swizzled LDS (conflict-free ds_read_b128), halo fused into
//     pad_x, vectorized pad_x.
// R2: fix LDS row stride in fragment reads (<<7 -> <<6).  conv: 51us, 0 bank
//     conflicts, but total 144us -> ~93us in pre-pass dispatches/overhead.
// R3: fuse pad_x + prep_w + conv into ONE cooperative kernel with grid.sync().
//     Grid 1024 = exact co-residency (LDS 33792B -> 4 blk/CU; VGPR capped 128
//     via __launch_bounds__(256,4)). Falls back to 3-kernel path if the
//     cooperative launch is rejected.

#define CIN   128
#define COUT  256
#define NBAT  16

typedef __bf16 bf16x8 __attribute__((ext_vector_type(8)));
typedef float f32x4 __attribute__((ext_vector_type(4)));

#define XPAD_ELEMS ((size_t)NBAT * 66 * 66 * CIN)       // 8,921,088
#define XPAD_BYTES (XPAD_ELEMS * 2)                      // 17,842,176
#define WT_ELEMS   ((size_t)9 * COUT * CIN)              // 294,912
#define WS_NEED    (XPAD_BYTES + WT_ELEMS * 2)

typedef __attribute__((address_space(1))) void gvoid;
typedef __attribute__((address_space(3))) void lvoid;

__device__ __forceinline__ void load_lds16(const void* g, void* l) {
    // async global->LDS, 16B per lane; LDS dest = wave-uniform base + lane*16
    __builtin_amdgcn_global_load_lds((gvoid*)g, (lvoid*)l, 16, 0, 0);
}

// ---------------------------------------------------------------------------
// Phase bodies (shared by fused cooperative kernel and 3-kernel fallback)
// ---------------------------------------------------------------------------

// W_eff = W + 2*B@A, cast bf16, layout Wt[tap][o][c] (c contig). idx<294912.
__device__ __forceinline__ void prepw_body(const float* __restrict__ W,
                                           const float* __restrict__ lA,
                                           const float* __restrict__ lB,
                                           __hip_bfloat16* __restrict__ Wt, int idx) {
    int c   = idx & 127;
    int o   = (idx >> 7) & 255;
    int tap = idx >> 15;                               // 0..8
    float acc = W[(o * 128 + c) * 9 + tap];
    float s = 0.f;
#pragma unroll
    for (int r = 0; r < 8; ++r)
        s += lB[o * 8 + r] * lA[r * 1152 + c * 9 + tap];
    acc += 2.0f * s;
    Wt[idx] = __float2bfloat16(acc);
}

// NCHW fp32 -> NHWC bf16 with +1 zero halo. One call per (n, input row h).
__device__ __forceinline__ void pad_body(const float* __restrict__ x,
                                         __bf16* __restrict__ xpad,
                                         float (*tile)[66], int n, int h, int t) {
    const float* src = x + (size_t)n * 128 * 4096 + (size_t)h * 64;
#pragma unroll
    for (int i = 0; i < 8; ++i) {                      // 2048 float4 total
        int g  = i * 256 + t;
        int c  = g >> 4;
        int w4 = (g & 15) * 4;
        const float4 v = *reinterpret_cast<const float4*>(src + (size_t)c * 4096 + w4);
        tile[c][w4 + 0] = v.x; tile[c][w4 + 1] = v.y;
        tile[c][w4 + 2] = v.z; tile[c][w4 + 3] = v.w;
    }
    __syncthreads();
    __bf16* dst = xpad + ((size_t)(n * 66 + h + 1) * 66 + 1) * 128;
#pragma unroll
    for (int i = 0; i < 4; ++i) {                      // 64w x 128c bf16 = 16KB
        int g  = i * 256 + t;
        int w  = g >> 4;
        int c0 = (g & 15) * 8;
        bf16x8 v;
#pragma unroll
        for (int j = 0; j < 8; ++j) v[j] = (__bf16)tile[c0 + j][w];
        *reinterpret_cast<bf16x8*>(dst + (size_t)w * 128 + c0) = v;
    }
    // halo: left/right pixel of this padded row
    bf16x8 z = {};
    __bf16* rowbase = xpad + (size_t)(n * 66 + h + 1) * 66 * 128;
    if (t < 32) {
        int ww = (t < 16) ? 0 : 65;
        int c0 = (t & 15) * 8;
        *reinterpret_cast<bf16x8*>(rowbase + (size_t)ww * 128 + c0) = z;
    }
    // top/bottom halo rows (full 66 px)
    if (h == 0 || h == 63) {
        __bf16* hrow = xpad + (size_t)(n * 66 + (h == 0 ? 0 : 65)) * 66 * 128;
        for (int i = t; i < 66 * 16; i += 256)
            *reinterpret_cast<bf16x8*>(hrow + (size_t)i * 8) = z;
    }
}

// Implicit-GEMM conv. Tile 128(o) x 128(pix), BK=64, XOR-swizzled LDS.
// Physical LDS chunk (16B) of logical (row, q) lives at q^(row&7); inverse
// permutation applied on per-lane GLOBAL addresses of global_load_lds so
// staging stays wave-uniform-base + lane*16.  pt: 0..511, ob: 0..1.
__device__ __forceinline__ void conv_body(const __bf16* __restrict__ xpad,
                                          const __bf16* __restrict__ Wt,
                                          const float* __restrict__ bias,
                                          float* __restrict__ out,
                                          __bf16* As, __bf16* Bs,
                                          int pt, int ob, int tid) {
    const int wv   = tid >> 6;
    const int lane = tid & 63;
    const int n     = pt >> 5;
    const int h0    = (pt & 31) << 1;                  // 2 output rows per tile
    const int obase = ob << 7;

    // per-lane swizzled source offset (elements), shared by A and B staging
    const int swz = ((lane >> 3) << 7) + ((((lane & 7) ^ (lane >> 3)) & 7) << 3);

    const __bf16* aG[4];
    const __bf16* bG[4];
#pragma unroll
    for (int j = 0; j < 4; ++j) {
        const int row0 = wv * 32 + j * 8;              // first row of this instr
        aG[j] = Wt + (obase + row0) * 128 + swz;
        const int p0 = row0;                           // pixel id 0..127
        bG[j] = xpad + (((size_t)(n * 66 + h0 + (p0 >> 6)) * 66 + (p0 & 63)) * 128) + swz;
    }

    const int wo = (wv >> 1) << 6;                     // o offset of wave
    const int wp = (wv & 1) << 6;                      // pix offset of wave

    int arow[4], brow[4], qo[2];
#pragma unroll
    for (int i = 0; i < 4; ++i) {
        arow[i] = (wo + i * 16 + (lane & 15)) << 6;    // LDS row = 64 elems
        brow[i] = (wp + i * 16 + (lane & 15)) << 6;
    }
#pragma unroll
    for (int s = 0; s < 2; ++s)
        qo[s] = ((((lane >> 4) + s * 4) ^ (lane & 7)) << 3);

    f32x4 acc[4][4] = {};

#pragma unroll
    for (int tap = 0; tap < 9; ++tap) {
        const int kh = tap / 3, kw = tap % 3;
        const int aoff_t = tap * (COUT * CIN);
        const int boff_t = (kh * 66 + kw) * 128;
#pragma unroll
        for (int cb = 0; cb < 2; ++cb) {
            const int ao = aoff_t + cb * 64;
            const int bo = boff_t + cb * 64;
            __syncthreads();                           // LDS free to overwrite
#pragma unroll
            for (int j = 0; j < 4; ++j) {
                load_lds16(aG[j] + ao, As + wv * 2048 + j * 512);
                load_lds16(bG[j] + bo, Bs + wv * 2048 + j * 512);
            }
            __syncthreads();                           // staging complete
#pragma unroll
            for (int s = 0; s < 2; ++s) {
                bf16x8 af[4], bfr[4];
#pragma unroll
                for (int i = 0; i < 4; ++i) {
                    af[i]  = *reinterpret_cast<const bf16x8*>(As + arow[i] + qo[s]);
                    bfr[i] = *reinterpret_cast<const bf16x8*>(Bs + brow[i] + qo[s]);
                }
#pragma unroll
                for (int mi = 0; mi < 4; ++mi)
#pragma unroll
                    for (int ni = 0; ni < 4; ++ni)
                        acc[mi][ni] = __builtin_amdgcn_mfma_f32_16x16x32_bf16(
                            af[mi], bfr[ni], acc[mi][ni], 0, 0, 0);
            }
        }
    }

    // epilogue: D row=(lane>>4)*4+j (o), col=lane&15 (pix); + bias
    const int col  = lane & 15;
    const int orow = (lane >> 4) << 2;
    const int h    = h0 + (wv & 1);                    // wp=64 <-> second row
#pragma unroll
    for (int mi = 0; mi < 4; ++mi) {
        const int obm = obase + wo + mi * 16 + orow;
#pragma unroll
        for (int j = 0; j < 4; ++j) {
            const int o = obm + j;
            const float bj = bias[o];
            float* orow_ptr = out + (((size_t)n * 256 + o) * 64 + h) * 64;
#pragma unroll
            for (int ni = 0; ni < 4; ++ni)
                orow_ptr[ni * 16 + col] = acc[mi][ni][j] + bj;
        }
    }
}

// ---------------------------------------------------------------------------
// Fused cooperative kernel: phase 1 (pad + prep_w), grid.sync, phase 2 (conv).
// Grid MUST be 1024 x 256: exact co-residency (4 blk/CU by LDS, VGPR<=128).
__global__ void __launch_bounds__(256, 4) fused_kernel(
    const float* __restrict__ x, const float* __restrict__ W,
    const float* __restrict__ b, const float* __restrict__ lA,
    const float* __restrict__ lB, __bf16* __restrict__ xpad,
    __hip_bfloat16* __restrict__ Wt, float* __restrict__ out) {
    __shared__ __align__(16) unsigned char smem[128 * 66 * 4];   // 33792 B
    const int bid = blockIdx.x;
    const int t   = threadIdx.x;

    // phase 1a: pad/convert one (n, h) row-block each
    pad_body(x, xpad, reinterpret_cast<float(*)[66]>(smem), bid >> 6, bid & 63, t);
    // phase 1b: fold LoRA into weights (1152 chunks over 1024 blocks)
    for (int chunk = bid; chunk < 1152; chunk += 1024)
        prepw_body(W, lA, lB, Wt, chunk * 256 + t);

    __threadfence();                                   // agent-scope release
    cooperative_groups::this_grid().sync();            // xpad/Wt visible to all

    // phase 2: conv
    conv_body(xpad, (const __bf16*)Wt, b, out,
              (__bf16*)smem, (__bf16*)smem + 8192, bid & 511, bid >> 9, t);
}

// ---------------------------------------------------------------------------
// Fallback path: 3 separate kernels (proven in R2)
__global__ void pad_x(const float* __restrict__ x, __bf16* __restrict__ xpad) {
    __shared__ float tile[128][66];
    pad_body(x, xpad, tile, blockIdx.x >> 6, blockIdx.x & 63, threadIdx.x);
}

__global__ void prep_w(const float* __restrict__ W, const float* __restrict__ lA,
                       const float* __restrict__ lB, __hip_bfloat16* __restrict__ Wt) {
    prepw_body(W, lA, lB, Wt, blockIdx.x * 256 + threadIdx.x);
}

__global__ void __launch_bounds__(256) conv_mfma(
    const __bf16* __restrict__ xpad, const __bf16* __restrict__ Wt,
    const float* __restrict__ bias, float* __restrict__ out) {
    __shared__ __align__(16) __bf16 AB[2][8192];
    conv_body(xpad, Wt, bias, out, AB[0], AB[1], blockIdx.x, blockIdx.y, threadIdx.x);
}

// Last-resort fallback (workspace too small): naive fp32.
__global__ void conv_naive(const float* __restrict__ x, const float* __restrict__ W,
                           const float* __restrict__ b, const float* __restrict__ lA,
                           const float* __restrict__ lB, float* __restrict__ out) {
    int idx = blockIdx.x * 256 + threadIdx.x;          // ((n*256+o)*64+h)*64+w
    int w = idx & 63, h = (idx >> 6) & 63, o = (idx >> 12) & 255, n = idx >> 20;
    float acc = b[o];
    float hr[8] = {0, 0, 0, 0, 0, 0, 0, 0};
    for (int c = 0; c < 128; ++c)
        for (int kh = 0; kh < 3; ++kh) {
            int hy = h + kh - 1;
            if (hy < 0 || hy > 63) continue;
            for (int kw = 0; kw < 3; ++kw) {
                int wx = w + kw - 1;
                if (wx < 0 || wx > 63) continue;
                float xv = x[((n * 128 + c) * 64 + hy) * 64 + wx];
                int ka = c * 9 + kh * 3 + kw;
                acc += W[(o * 128 + c) * 9 + kh * 3 + kw] * xv;
#pragma unroll
                for (int r = 0; r < 8; ++r) hr[r] += lA[r * 1152 + ka] * xv;
            }
        }
    float ls = 0.f;
#pragma unroll
    for (int r = 0; r < 8; ++r) ls += lB[o * 8 + r] * hr[r];
    out[idx] = acc + 2.0f * ls;
}

// ---------------------------------------------------------------------------
extern "C" void kernel_launch(void* const* d_in, const int* in_sizes, int n_in,
                              void* d_out, int out_size, void* d_ws, size_t ws_size,
                              hipStream_t stream) {
    const float* x  = (const float*)d_in[0];
    const float* W  = (const float*)d_in[1];
    const float* b  = (const float*)d_in[2];
    const float* lA = (const float*)d_in[3];
    const float* lB = (const float*)d_in[4];
    float* out = (float*)d_out;

    if (ws_size < WS_NEED) {
        conv_naive<<<out_size / 256, 256, 0, stream>>>(x, W, b, lA, lB, out);
        return;
    }

    __bf16* xpad = (__bf16*)d_ws;
    __hip_bfloat16* Wt = (__hip_bfloat16*)((char*)d_ws + XPAD_BYTES);

    void* args[] = {(void*)&x, (void*)&W, (void*)&b, (void*)&lA, (void*)&lB,
                    (void*)&xpad, (void*)&Wt, (void*)&out};
    hipError_t err = hipLaunchCooperativeKernel(fused_kernel, dim3(1024), dim3(256),
                                                args, 0, stream);
    if (err != hipSuccess) {
        // fallback: proven 3-kernel path
        pad_x<<<NBAT * 64, 256, 0, stream>>>(x, xpad);
        prep_w<<<(int)(WT_ELEMS / 256), 256, 0, stream>>>(W, lA, lB, Wt);
        conv_mfma<<<dim3(512, 2), 256, 0, stream>>>(xpad, (const __bf16*)Wt, b, out);
    }
}

// Round 5
// 233.492 us; speedup vs baseline: 1.5918x; 1.5918x over previous
//
#include <hip/hip_runtime.h>
#include <hip/hip_bf16.h>

// Conv2dWithLoRA: out = conv3x3(x, W_eff) + b, where W_eff = W + 2.0 * B@A.
// LoRA folded into weights -> single implicit-GEMM conv, bf16 MFMA, fp32 accum.
// M = 16*64*64 = 65536 pixels, N = 256 outs, K = 128*9 = 1152.
// R2: 4-wave 128x128 LDS tile conv: 51us, total 144us.
// R4: cooperative fusion REGRESSED (grid.sync ~225us). Learned: total-kernel
//     ~94us is fixed harness overhead, independent of node count. Only conv
//     time is controllable.
// R5: single-wave (64-thread) blocks, register-direct MFMA fragments via
//     global_load_dwordx4 (A[o][c] and xpad[px][c] are K-contiguous: each
//     fragment is 16B contiguous). No LDS, no barriers, no vmcnt(0) drains.
//     4096 blocks, ~12/CU co-resident; TLP hides load latency. pad+prep
//     merged into one kernel (2 graph nodes total).

#define CIN   128
#define COUT  256
#define NBAT  16

typedef __bf16 bf16x8 __attribute__((ext_vector_type(8)));
typedef float f32x4 __attribute__((ext_vector_type(4)));

#define XPAD_ELEMS ((size_t)NBAT * 66 * 66 * CIN)       // 8,921,088
#define XPAD_BYTES (XPAD_ELEMS * 2)                      // 17,842,176 (16B-mult)
#define WT_ELEMS   ((size_t)9 * COUT * CIN)              // 294,912
#define WS_NEED    (XPAD_BYTES + WT_ELEMS * 2)

// ---------------------------------------------------------------------------
// Phase 1 (merged): pad/convert x + fold LoRA into weights.
// Grid 1024 x 256. Block (n=bid>>6, h=bid&63) pads one image row-block;
// blocks also cover the 1152 weight chunks strided by 1024.
__global__ void pad_prep(const float* __restrict__ x, const float* __restrict__ W,
                         const float* __restrict__ lA, const float* __restrict__ lB,
                         __bf16* __restrict__ xpad, __bf16* __restrict__ Wt) {
    __shared__ float tile[128][66];                    // stride 66: benign reads
    const int bid = blockIdx.x;
    const int n = bid >> 6;
    const int h = bid & 63;
    const int t = threadIdx.x;

    // --- pad/convert: NCHW fp32 row h -> NHWC bf16 row h+1 with halo ---
    const float* src = x + (size_t)n * 128 * 4096 + (size_t)h * 64;
#pragma unroll
    for (int i = 0; i < 8; ++i) {                      // 2048 float4 total
        int g  = i * 256 + t;
        int c  = g >> 4;
        int w4 = (g & 15) * 4;
        const float4 v = *reinterpret_cast<const float4*>(src + (size_t)c * 4096 + w4);
        tile[c][w4 + 0] = v.x; tile[c][w4 + 1] = v.y;
        tile[c][w4 + 2] = v.z; tile[c][w4 + 3] = v.w;
    }
    __syncthreads();
    __bf16* dst = xpad + ((size_t)(n * 66 + h + 1) * 66 + 1) * 128;
#pragma unroll
    for (int i = 0; i < 4; ++i) {                      // 64w x 128c bf16 = 16KB
        int g  = i * 256 + t;
        int w  = g >> 4;
        int c0 = (g & 15) * 8;
        bf16x8 v;
#pragma unroll
        for (int j = 0; j < 8; ++j) v[j] = (__bf16)tile[c0 + j][w];
        *reinterpret_cast<bf16x8*>(dst + (size_t)w * 128 + c0) = v;
    }
    bf16x8 z = {};
    __bf16* rowbase = xpad + (size_t)(n * 66 + h + 1) * 66 * 128;
    if (t < 32) {                                      // left/right halo pixel
        int ww = (t < 16) ? 0 : 65;
        int c0 = (t & 15) * 8;
        *reinterpret_cast<bf16x8*>(rowbase + (size_t)ww * 128 + c0) = z;
    }
    if (h == 0 || h == 63) {                           // top/bottom halo rows
        __bf16* hrow = xpad + (size_t)(n * 66 + (h == 0 ? 0 : 65)) * 66 * 128;
        for (int i = t; i < 66 * 16; i += 256)
            *reinterpret_cast<bf16x8*>(hrow + (size_t)i * 8) = z;
    }

    // --- weight fold: Wt[tap][o][c] = bf16(W + 2*B@A), 1152 chunks ---
    for (int chunk = bid; chunk < 1152; chunk += 1024) {
        int idx = chunk * 256 + t;
        int c   = idx & 127;
        int o   = (idx >> 7) & 255;
        int tap = idx >> 15;                           // 0..8
        float acc = W[(o * 128 + c) * 9 + tap];
        float s = 0.f;
#pragma unroll
        for (int r = 0; r < 8; ++r)
            s += lB[o * 8 + r] * lA[r * 1152 + c * 9 + tap];
        Wt[idx] = (__bf16)(acc + 2.0f * s);
    }
}

// ---------------------------------------------------------------------------
// Phase 2: implicit-GEMM conv, one 64-lane wave per block, 64(o) x 64(px=one
// output row) tile, register-direct fragments (no LDS, no barriers).
// Grid 4096 flat; swizzle puts the 4 o-tiles of one pixel row on one XCD.
__global__ void __launch_bounds__(64, 3) conv_rdirect(
    const __bf16* __restrict__ xpad, const __bf16* __restrict__ Wt,
    const float* __restrict__ bias, float* __restrict__ out) {
    const int bid = blockIdx.x;
    const int p   = bid & 7;                           // XCD phase
    const int nb  = (bid >> 3) & 3;                    // o tile (shares B w/ same pt)
    const int r   = bid >> 5;
    const int pt  = (r << 3) | p;                      // 0..1023
    const int n   = pt >> 6;
    const int h   = pt & 63;                           // output row
    const int obase = nb << 6;

    const int lane = threadIdx.x;                      // 0..63
    const int m    = lane & 15;                        // row-in-16 (o or px)
    const int kq   = (lane >> 4) * 8;                  // k chunk base (8 elems)

    // A[m=lane&15][k=kq+j] and B[k=kq+j][n=lane&15]: both 16B contiguous.
    const __bf16* aB = Wt + (obase + m) * 128 + kq;
    const __bf16* bB = xpad + ((size_t)(n * 66 + h) * 66 + m) * 128 + kq;

    f32x4 acc[4][4] = {};

#pragma unroll
    for (int kh = 0; kh < 3; ++kh) {
#pragma unroll
        for (int kw = 0; kw < 3; ++kw) {
            const int tap = kh * 3 + kw;
            const __bf16* a0 = aB + tap * (COUT * CIN);
            const __bf16* b0 = bB + (kh * 66 + kw) * 128;
#pragma unroll
            for (int cb = 0; cb < 2; ++cb) {           // c half (K=64 per tap-half)
                bf16x8 af[4][2], bfr[4][2];
#pragma unroll
                for (int i = 0; i < 4; ++i)
#pragma unroll
                    for (int s = 0; s < 2; ++s) {
                        af[i][s]  = *reinterpret_cast<const bf16x8*>(a0 + i * 2048 + cb * 64 + s * 32);
                        bfr[i][s] = *reinterpret_cast<const bf16x8*>(b0 + i * 2048 + cb * 64 + s * 32);
                    }
#pragma unroll
                for (int s = 0; s < 2; ++s)
#pragma unroll
                    for (int mi = 0; mi < 4; ++mi)
#pragma unroll
                        for (int ni = 0; ni < 4; ++ni)
                            acc[mi][ni] = __builtin_amdgcn_mfma_f32_16x16x32_bf16(
                                af[mi][s], bfr[ni][s], acc[mi][ni], 0, 0, 0);
            }
        }
    }

    // epilogue: D row=(lane>>4)*4+j (o), col=lane&15 (px); + bias
    const int orow = (lane >> 4) << 2;
#pragma unroll
    for (int mi = 0; mi < 4; ++mi) {
        const int obm = obase + mi * 16 + orow;
#pragma unroll
        for (int j = 0; j < 4; ++j) {
            const int o = obm + j;
            const float bj = bias[o];
            float* op = out + (((size_t)n * 256 + o) * 64 + h) * 64;
#pragma unroll
            for (int ni = 0; ni < 4; ++ni)
                op[ni * 16 + m] = acc[mi][ni][j] + bj;
        }
    }
}

// ---------------------------------------------------------------------------
// Last-resort fallback (workspace too small): naive fp32.
__global__ void conv_naive(const float* __restrict__ x, const float* __restrict__ W,
                           const float* __restrict__ b, const float* __restrict__ lA,
                           const float* __restrict__ lB, float* __restrict__ out) {
    int idx = blockIdx.x * 256 + threadIdx.x;          // ((n*256+o)*64+h)*64+w
    int w = idx & 63, h = (idx >> 6) & 63, o = (idx >> 12) & 255, n = idx >> 20;
    float acc = b[o];
    float hr[8] = {0, 0, 0, 0, 0, 0, 0, 0};
    for (int c = 0; c < 128; ++c)
        for (int kh = 0; kh < 3; ++kh) {
            int hy = h + kh - 1;
            if (hy < 0 || hy > 63) continue;
            for (int kw = 0; kw < 3; ++kw) {
                int wx = w + kw - 1;
                if (wx < 0 || wx > 63) continue;
                float xv = x[((n * 128 + c) * 64 + hy) * 64 + wx];
                int ka = c * 9 + kh * 3 + kw;
                acc += W[(o * 128 + c) * 9 + kh * 3 + kw] * xv;
#pragma unroll
                for (int r = 0; r < 8; ++r) hr[r] += lA[r * 1152 + ka] * xv;
            }
        }
    float ls = 0.f;
#pragma unroll
    for (int r = 0; r < 8; ++r) ls += lB[o * 8 + r] * hr[r];
    out[idx] = acc + 2.0f * ls;
}

// ---------------------------------------------------------------------------
extern "C" void kernel_launch(void* const* d_in, const int* in_sizes, int n_in,
                              void* d_out, int out_size, void* d_ws, size_t ws_size,
                              hipStream_t stream) {
    const float* x  = (const float*)d_in[0];
    const float* W  = (const float*)d_in[1];
    const float* b  = (const float*)d_in[2];
    const float* lA = (const float*)d_in[3];
    const float* lB = (const float*)d_in[4];
    float* out = (float*)d_out;

    if (ws_size < WS_NEED) {
        conv_naive<<<out_size / 256, 256, 0, stream>>>(x, W, b, lA, lB, out);
        return;
    }

    __bf16* xpad = (__bf16*)d_ws;
    __bf16* Wt   = (__bf16*)((char*)d_ws + XPAD_BYTES);

    pad_prep<<<1024, 256, 0, stream>>>(x, W, lA, lB, xpad, Wt);
    conv_rdirect<<<4096, 64, 0, stream>>>(xpad, Wt, b, out);
}

// Round 6
// 194.768 us; speedup vs baseline: 1.9083x; 1.1988x over previous
//
#include <hip/hip_runtime.h>
#include <hip/hip_bf16.h>

// Conv2dWithLoRA: out = conv3x3(x, W_eff) + b, where W_eff = W + 2.0 * B@A.
// LoRA folded into weights -> single implicit-GEMM conv, bf16 MFMA, fp32 accum.
// R2: 4-wave 128x128 LDS tile, BK=64: conv 51us (758 TF), total 144us.
// R4: cooperative fusion regressed (grid.sync ~225us). ~94us of total is fixed
//     harness overhead independent of node count.
// R5: all-register-direct regressed (202us): VGPR collapsed to 80, loads
//     serialized at L2 latency. Bulk async staging (global_load_lds) is key.
// R6: keep R2's 4-wave block + global_load_lds for B, but stage the FULL
//     66-px padded row-pair once per (kh, c-half) -> all 3 kw taps read it:
//     B staging cut 3x, barriers 36 -> 12, 96 MFMA per barrier-pair.
//     A (576 KB, L2-resident) is register-direct: 8 dwordx4 per 32 MFMAs.

#define CIN   128
#define COUT  256
#define NBAT  16

typedef __bf16 bf16x8 __attribute__((ext_vector_type(8)));
typedef float f32x4 __attribute__((ext_vector_type(4)));

#define XPAD_ELEMS ((size_t)NBAT * 66 * 66 * CIN)       // 8,921,088
#define XPAD_BYTES (XPAD_ELEMS * 2)                      // 17,842,176
#define WT_ELEMS   ((size_t)9 * COUT * CIN)              // 294,912
// staging overreads up to ~512B past xpad (lands in Wt); Wt tail slack +1KB
#define WS_NEED    (XPAD_BYTES + WT_ELEMS * 2 + 1024)

typedef __attribute__((address_space(1))) void gvoid;
typedef __attribute__((address_space(3))) void lvoid;

__device__ __forceinline__ void load_lds16(const void* g, void* l) {
    // async global->LDS, 16B per lane; LDS dest = wave-uniform base + lane*16
    __builtin_amdgcn_global_load_lds((gvoid*)g, (lvoid*)l, 16, 0, 0);
}

// ---------------------------------------------------------------------------
// Phase 1 (merged): pad/convert x + fold LoRA into weights.
// Grid 1024 x 256. Block (n=bid>>6, h=bid&63) pads one image row-block;
// blocks also cover the 1152 weight chunks strided by 1024.
__global__ void pad_prep(const float* __restrict__ x, const float* __restrict__ W,
                         const float* __restrict__ lA, const float* __restrict__ lB,
                         __bf16* __restrict__ xpad, __bf16* __restrict__ Wt) {
    __shared__ float tile[128][66];
    const int bid = blockIdx.x;
    const int n = bid >> 6;
    const int h = bid & 63;
    const int t = threadIdx.x;

    const float* src = x + (size_t)n * 128 * 4096 + (size_t)h * 64;
#pragma unroll
    for (int i = 0; i < 8; ++i) {                      // 2048 float4 total
        int g  = i * 256 + t;
        int c  = g >> 4;
        int w4 = (g & 15) * 4;
        const float4 v = *reinterpret_cast<const float4*>(src + (size_t)c * 4096 + w4);
        tile[c][w4 + 0] = v.x; tile[c][w4 + 1] = v.y;
        tile[c][w4 + 2] = v.z; tile[c][w4 + 3] = v.w;
    }
    __syncthreads();
    __bf16* dst = xpad + ((size_t)(n * 66 + h + 1) * 66 + 1) * 128;
#pragma unroll
    for (int i = 0; i < 4; ++i) {                      // 64w x 128c bf16
        int g  = i * 256 + t;
        int w  = g >> 4;
        int c0 = (g & 15) * 8;
        bf16x8 v;
#pragma unroll
        for (int j = 0; j < 8; ++j) v[j] = (__bf16)tile[c0 + j][w];
        *reinterpret_cast<bf16x8*>(dst + (size_t)w * 128 + c0) = v;
    }
    bf16x8 z = {};
    __bf16* rowbase = xpad + (size_t)(n * 66 + h + 1) * 66 * 128;
    if (t < 32) {                                      // left/right halo pixel
        int ww = (t < 16) ? 0 : 65;
        int c0 = (t & 15) * 8;
        *reinterpret_cast<bf16x8*>(rowbase + (size_t)ww * 128 + c0) = z;
    }
    if (h == 0 || h == 63) {                           // top/bottom halo rows
        __bf16* hrow = xpad + (size_t)(n * 66 + (h == 0 ? 0 : 65)) * 66 * 128;
        for (int i = t; i < 66 * 16; i += 256)
            *reinterpret_cast<bf16x8*>(hrow + (size_t)i * 8) = z;
    }

    for (int chunk = bid; chunk < 1152; chunk += 1024) {
        int idx = chunk * 256 + t;
        int c   = idx & 127;
        int o   = (idx >> 7) & 255;
        int tap = idx >> 15;                           // 0..8
        float acc = W[(o * 128 + c) * 9 + tap];
        float s = 0.f;
#pragma unroll
        for (int r = 0; r < 8; ++r)
            s += lB[o * 8 + r] * lA[r * 1152 + c * 9 + tap];
        Wt[idx] = (__bf16)(acc + 2.0f * s);
    }
}

// ---------------------------------------------------------------------------
// Phase 2: implicit-GEMM conv. 128(o) x 128(px = 2 output rows) per block,
// 4 waves (wave = 64o x 64px). 6 stages (3 kh x 2 c-half); per stage, B =
// padded row-pair, full 66 px (as 2x68 j-rows x 64c = 17KB LDS, XOR-swizzled
// on j&7), staged once and reused by all 3 kw taps. A register-direct.
__global__ void __launch_bounds__(256, 4) conv_mfma2(
    const __bf16* __restrict__ xpad, const __bf16* __restrict__ Wt,
    const float* __restrict__ bias, float* __restrict__ out) {
    __shared__ __align__(16) __bf16 Bs[136 * 64];      // 17,408 B

    const int tid  = threadIdx.x;
    const int wv   = tid >> 6;
    const int lane = tid & 63;

    const int pt    = blockIdx.x;                      // 0..511
    const int ob    = blockIdx.y;                      // 0..1
    const int n     = pt >> 5;
    const int h0    = (pt & 31) << 1;                  // 2 output rows
    const int obase = ob << 7;

    const int wo   = (wv >> 1) << 6;                   // wave o offset
    const int wrow = wv & 1;                           // wave output row (0/1)

    // A register-direct: frag(mi,s) = 16B at aP[mi] + tap*32768 + cb*64 + s*32
    const __bf16* aP[4];
#pragma unroll
    for (int mi = 0; mi < 4; ++mi)
        aP[mi] = Wt + (obase + wo + mi * 16 + (lane & 15)) * 128 + (lane >> 4) * 8;

    // B staging per-lane invariants: op k covers j-rows k*8..k*8+7
    // j = k*8 + (lane>>3); r = j>=68; p = j - 68r; logical chunk = (lane&7)^(j&7)
    // global = xpad + ((n*66 + h0 + kh + r)*66 + p)*128 + cb*64 + logical*8

    f32x4 acc[4][4] = {};

#pragma unroll
    for (int kh = 0; kh < 3; ++kh) {
#pragma unroll
        for (int cb = 0; cb < 2; ++cb) {
            __syncthreads();                           // prior-stage reads done
#pragma unroll
            for (int k = wv; k < 17; k += 4) {
                const int j  = k * 8 + (lane >> 3);
                const int r  = (j >= 68) ? 1 : 0;
                const int p  = j - 68 * r;
                const int lg = (((lane & 7) ^ (j & 7)) << 3);
                const __bf16* g = xpad +
                    ((size_t)((n * 66 + h0 + kh + r) * 66 + p)) * 128 + cb * 64 + lg;
                load_lds16(g, &Bs[k * 512]);
            }
            __syncthreads();                           // staging visible

            const int aoff_kh = (kh * 3) * (COUT * CIN) + cb * 64;
#pragma unroll
            for (int kw = 0; kw < 3; ++kw) {
                const int ta = aoff_kh + kw * (COUT * CIN);
#pragma unroll
                for (int s = 0; s < 2; ++s) {
                    bf16x8 af[4], bfr[4];
#pragma unroll
                    for (int mi = 0; mi < 4; ++mi)
                        af[mi] = *reinterpret_cast<const bf16x8*>(aP[mi] + ta + s * 32);
#pragma unroll
                    for (int i = 0; i < 4; ++i) {
                        const int j    = wrow * 68 + (lane & 15) + i * 16 + kw;
                        const int phys = ((((lane >> 4) + s * 4) ^ (j & 7)) << 3);
                        bfr[i] = *reinterpret_cast<const bf16x8*>(&Bs[j * 64 + phys]);
                    }
#pragma unroll
                    for (int mi = 0; mi < 4; ++mi)
#pragma unroll
                        for (int ni = 0; ni < 4; ++ni)
                            acc[mi][ni] = __builtin_amdgcn_mfma_f32_16x16x32_bf16(
                                af[mi], bfr[ni], acc[mi][ni], 0, 0, 0);
                }
            }
        }
    }

    // epilogue: D row=(lane>>4)*4+j (o), col=lane&15 (px); + bias
    const int col  = lane & 15;
    const int orow = (lane >> 4) << 2;
    const int h    = h0 + wrow;
#pragma unroll
    for (int mi = 0; mi < 4; ++mi) {
        const int obm = obase + wo + mi * 16 + orow;
#pragma unroll
        for (int j = 0; j < 4; ++j) {
            const int o = obm + j;
            const float bj = bias[o];
            float* op = out + (((size_t)n * 256 + o) * 64 + h) * 64;
#pragma unroll
            for (int ni = 0; ni < 4; ++ni)
                op[ni * 16 + col] = acc[mi][ni][j] + bj;
        }
    }
}

// ---------------------------------------------------------------------------
// Last-resort fallback (workspace too small): naive fp32.
__global__ void conv_naive(const float* __restrict__ x, const float* __restrict__ W,
                           const float* __restrict__ b, const float* __restrict__ lA,
                           const float* __restrict__ lB, float* __restrict__ out) {
    int idx = blockIdx.x * 256 + threadIdx.x;          // ((n*256+o)*64+h)*64+w
    int w = idx & 63, h = (idx >> 6) & 63, o = (idx >> 12) & 255, n = idx >> 20;
    float acc = b[o];
    float hr[8] = {0, 0, 0, 0, 0, 0, 0, 0};
    for (int c = 0; c < 128; ++c)
        for (int kh = 0; kh < 3; ++kh) {
            int hy = h + kh - 1;
            if (hy < 0 || hy > 63) continue;
            for (int kw = 0; kw < 3; ++kw) {
                int wx = w + kw - 1;
                if (wx < 0 || wx > 63) continue;
                float xv = x[((n * 128 + c) * 64 + hy) * 64 + wx];
                int ka = c * 9 + kh * 3 + kw;
                acc += W[(o * 128 + c) * 9 + kh * 3 + kw] * xv;
#pragma unroll
                for (int r = 0; r < 8; ++r) hr[r] += lA[r * 1152 + ka] * xv;
            }
        }
    float ls = 0.f;
#pragma unroll
    for (int r = 0; r < 8; ++r) ls += lB[o * 8 + r] * hr[r];
    out[idx] = acc + 2.0f * ls;
}

// ---------------------------------------------------------------------------
extern "C" void kernel_launch(void* const* d_in, const int* in_sizes, int n_in,
                              void* d_out, int out_size, void* d_ws, size_t ws_size,
                              hipStream_t stream) {
    const float* x  = (const float*)d_in[0];
    const float* W  = (const float*)d_in[1];
    const float* b  = (const float*)d_in[2];
    const float* lA = (const float*)d_in[3];
    const float* lB = (const float*)d_in[4];
    float* out = (float*)d_out;

    if (ws_size < WS_NEED) {
        conv_naive<<<out_size / 256, 256, 0, stream>>>(x, W, b, lA, lB, out);
        return;
    }

    __bf16* xpad = (__bf16*)d_ws;
    __bf16* Wt   = (__bf16*)((char*)d_ws + XPAD_BYTES);

    pad_prep<<<1024, 256, 0, stream>>>(x, W, lA, lB, xpad, Wt);
    conv_mfma2<<<dim3(512, 2), 256, 0, stream>>>(xpad, Wt, b, out);
}